// Round 1
// baseline (288.220 us; speedup 1.0000x reference)
//
#include <hip/hip_runtime.h>
#include <math.h>

#define NB 32           // batch
#define SEG_BLOCKS 2048

// ---------- math helpers (match reference semantics) ----------

__device__ __forceinline__ float bce_logits(float x, float y) {
    // max(x,0) - x*y + log1p(exp(-|x|))
    float a = fabsf(x);
    return fmaxf(x, 0.f) - x * y + __logf(1.f + __expf(-a));
}

__device__ __forceinline__ float focal_elt(float x, float t) {
    // t is exactly 0.0 or 1.0 (one-hot)
    float p = 1.f / (1.f + __expf(-x));
    float ce = bce_logits(x, t);
    float p_t = (t > 0.5f) ? p : (1.f - p);
    float a_t = (t > 0.5f) ? 0.25f : 0.75f;
    float om = 1.f - p_t;
    return a_t * om * om * ce;
}

// Block reduction for N floats, blockDim.x == 256 (4 waves of 64).
template <int N>
__device__ void blk_reduce_arr(float* v) {
    __shared__ float sm[N][4];
    int lane = threadIdx.x & 63;
    int wid  = threadIdx.x >> 6;
#pragma unroll
    for (int j = 0; j < N; j++) {
        float x = v[j];
#pragma unroll
        for (int off = 32; off > 0; off >>= 1) x += __shfl_down(x, off, 64);
        if (lane == 0) sm[j][wid] = x;
    }
    __syncthreads();
    if (threadIdx.x == 0) {
#pragma unroll
        for (int j = 0; j < N; j++) {
            float s = 0.f;
#pragma unroll
            for (int w = 0; w < 4; w++) s += sm[j][w];
            v[j] = s;
        }
    }
}

// ---------- seg loss: BCE over (B,4,512,512) vs broadcast mask ----------

__global__ __launch_bounds__(256) void seg_kernel(
        const float* __restrict__ logits, const int* __restrict__ mask,
        float* __restrict__ partial) {
    const int HW  = 512 * 512;   // 262144
    const int QPI = HW / 4;      // 65536 quads per image
    const int TOTQ = NB * QPI;   // 2,097,152
    int tid = blockIdx.x * 256 + threadIdx.x;
    float acc = 0.f;
    for (int q = tid; q < TOTQ; q += SEG_BLOCKS * 256) {
        int b   = q >> 16;       // q / 65536
        int hwq = q & 65535;
        const int4 m4 = ((const int4*)(mask + (size_t)b * HW))[hwq];
        float ty0 = (float)m4.x, ty1 = (float)m4.y, ty2 = (float)m4.z, ty3 = (float)m4.w;
        const float4* base = (const float4*)(logits + (size_t)b * 4 * HW);
#pragma unroll
        for (int c = 0; c < 4; c++) {
            float4 x4 = base[c * QPI + hwq];
            acc += bce_logits(x4.x, ty0) + bce_logits(x4.y, ty1)
                 + bce_logits(x4.z, ty2) + bce_logits(x4.w, ty3);
        }
    }
    float v[1] = {acc};
    blk_reduce_arr<1>(v);
    if (threadIdx.x == 0) partial[blockIdx.x] = v[0];
}

// ---------- per-(image,scale) detection partial sums ----------
// writes 4 floats per (scale, image): {cls_sum, reg_masked_sum, cen_masked_sum, npos}

__global__ __launch_bounds__(256) void det_kernel(
        const float* __restrict__ cls0, const float* __restrict__ cls1, const float* __restrict__ cls2,
        const float* __restrict__ reg0, const float* __restrict__ reg1, const float* __restrict__ reg2,
        const float* __restrict__ cen0, const float* __restrict__ cen1, const float* __restrict__ cen2,
        const float* __restrict__ boxes, const int* __restrict__ labels,
        float* __restrict__ outws) {
    const int b = blockIdx.x;
    const int s = blockIdx.y;
    int Wd, shift, L; float stride;
    const float *cls, *reg, *cen;
    if (s == 0)      { Wd = 64; shift = 6; L = 4096; stride = 8.f;  cls = cls0; reg = reg0; cen = cen0; }
    else if (s == 1) { Wd = 32; shift = 5; L = 1024; stride = 16.f; cls = cls1; reg = reg1; cen = cen1; }
    else             { Wd = 16; shift = 4; L = 256;  stride = 32.f; cls = cls2; reg = reg2; cen = cen2; }

    __shared__ float sx0[20], sy0[20], sx1[20], sy1[20], sar[20];
    __shared__ int   slb[20];
    if (threadIdx.x < 20) {
        int k = threadIdx.x;
        const float* bb = boxes + (b * 20 + k) * 4;
        float cx = bb[0] * 512.f, cy = bb[1] * 512.f;
        float w  = bb[2] * 512.f, h  = bb[3] * 512.f;
        float x0 = cx - 0.5f * w, y0 = cy - 0.5f * h;
        float x1 = cx + 0.5f * w, y1 = cy + 0.5f * h;
        sx0[k] = x0; sy0[k] = y0; sx1[k] = x1; sy1[k] = y1;
        sar[k] = (x1 - x0) * (y1 - y0);
        slb[k] = labels[b * 20 + k];
    }
    __syncthreads();

    const float* clsb = cls + (size_t)b * 5 * L;
    const float* regb = reg + (size_t)b * 4 * L;
    const float* cenb = cen + (size_t)b * L;
    const float inv = 1.f / stride;

    float cls_s = 0.f, reg_s = 0.f, cen_s = 0.f, np = 0.f;
    for (int l = threadIdx.x; l < L; l += 256) {
        float lx = ((l & (Wd - 1)) + 0.5f) * stride;
        float ly = ((l >> shift)   + 0.5f) * stride;
        int bk = -1; float ba = INFINITY;
        float bl = 0.f, btp = 0.f, brr = 0.f, bbt = 0.f;
#pragma unroll
        for (int k = 0; k < 20; k++) {
            float li = lx - sx0[k], ti = ly - sy0[k];
            float ri = sx1[k] - lx, bi = sy1[k] - ly;
            float mn = fminf(fminf(li, ti), fminf(ri, bi));
            if (mn > 0.f && sar[k] < ba) {   // strict '<' == first-occurrence argmin
                ba = sar[k]; bk = k;
                bl = li; btp = ti; brr = ri; bbt = bi;
            }
        }
        int tl = (bk >= 0) ? slb[bk] : -1;
#pragma unroll
        for (int c = 0; c < 4; c++) {
            float x = clsb[(c + 1) * L + l];   // channel 0 dropped by reference
            cls_s += focal_elt(x, (c == tl) ? 1.f : 0.f);
        }
        if (bk >= 0) {
            float r0 = bl * inv, r1 = btp * inv, r2 = brr * inv, r3 = bbt * inv;
            float d0 = regb[0 * L + l] - r0;
            float d1 = regb[1 * L + l] - r1;
            float d2 = regb[2 * L + l] - r2;
            float d3 = regb[3 * L + l] - r3;
            float a0 = fabsf(d0), a1 = fabsf(d1), a2 = fabsf(d2), a3 = fabsf(d3);
            float sl = (a0 < 1.f ? 0.5f * d0 * d0 : a0 - 0.5f)
                     + (a1 < 1.f ? 0.5f * d1 * d1 : a1 - 0.5f)
                     + (a2 < 1.f ? 0.5f * d2 * d2 : a2 - 0.5f)
                     + (a3 < 1.f ? 0.5f * d3 * d3 : a3 - 0.5f);
            reg_s += 0.25f * sl;
            float mnlr = fminf(r0, r2), mxlr = fmaxf(r0, r2);
            float mntb = fminf(r1, r3), mxtb = fmaxf(r1, r3);
            float v = (mnlr / (mxlr + 1e-6f)) * (mntb / (mxtb + 1e-6f));
            v = fminf(fmaxf(v, 0.f), 1.f);
            float ct = sqrtf(v);
            cen_s += bce_logits(cenb[l], ct);
            np += 1.f;
        }
    }

    float v4[4] = {cls_s, reg_s, cen_s, np};
    blk_reduce_arr<4>(v4);
    if (threadIdx.x == 0) {
        float* o = outws + (size_t)(s * NB + b) * 4;
        o[0] = v4[0]; o[1] = v4[1]; o[2] = v4[2]; o[3] = v4[3];
    }
}

// ---------- final combine: seg partials + cls focal + det normalization ----------

__global__ __launch_bounds__(256) void final_kernel(
        const float* __restrict__ segpart, const float* __restrict__ detws,
        const float* __restrict__ cls_pred, const int* __restrict__ cls_target,
        float* __restrict__ out) {
    float segs = 0.f;
    for (int i = threadIdx.x; i < SEG_BLOCKS; i += 256) segs += segpart[i];
    float clss = 0.f;
    for (int e = threadIdx.x; e < NB * 10; e += 256) {
        int i = e / 10, c = e - i * 10;
        clss += focal_elt(cls_pred[e], (cls_target[i] == c) ? 1.f : 0.f);
    }
    float v2[2] = {segs, clss};
    blk_reduce_arr<2>(v2);
    if (threadIdx.x == 0) {
        float seg_loss = v2[0] / 33554432.f;   // B*4*512*512
        float cls_loss = v2[1] / 320.f;        // B*10
        const int Ls[3] = {4096, 1024, 256};
        float tc = 0.f, tr = 0.f, tn = 0.f;
        for (int s = 0; s < 3; s++) {
            float ac = 0.f, ar = 0.f, an = 0.f;
            for (int i = 0; i < NB; i++) {
                const float* o = detws + (size_t)(s * NB + i) * 4;
                ac += o[0] / (Ls[s] * 4.f);
                float np = o[3];
                float denom = fmaxf(np, 1.f);
                if (np > 0.f) {
                    ar += o[1] / denom;
                    an += o[2] / denom;
                }
            }
            tc += ac / (float)NB;
            tr += ar / (float)NB;
            tn += an / (float)NB;
        }
        float det_loss = (tc + tr + tn) / 3.f;
        out[0] = seg_loss + det_loss + 0.5f * cls_loss;   // W_SEG=1, W_DET=1, W_CLS=0.5
    }
}

// ---------- launch ----------

extern "C" void kernel_launch(void* const* d_in, const int* in_sizes, int n_in,
                              void* d_out, int out_size, void* d_ws, size_t ws_size,
                              hipStream_t stream) {
    const float* seg_logits = (const float*)d_in[0];
    const int*   seg_mask   = (const int*)d_in[1];
    const float* cls0 = (const float*)d_in[2];
    const float* cls1 = (const float*)d_in[3];
    const float* cls2 = (const float*)d_in[4];
    const float* reg0 = (const float*)d_in[5];
    const float* reg1 = (const float*)d_in[6];
    const float* reg2 = (const float*)d_in[7];
    const float* cen0 = (const float*)d_in[8];
    const float* cen1 = (const float*)d_in[9];
    const float* cen2 = (const float*)d_in[10];
    const float* boxes  = (const float*)d_in[11];
    const int*   labels = (const int*)d_in[12];
    const float* cls_pred   = (const float*)d_in[13];
    const int*   cls_target = (const int*)d_in[14];

    float* ws      = (float*)d_ws;
    float* segpart = ws;                 // SEG_BLOCKS floats
    float* detws   = ws + SEG_BLOCKS;    // 3*32*4 floats

    seg_kernel<<<SEG_BLOCKS, 256, 0, stream>>>(seg_logits, seg_mask, segpart);
    det_kernel<<<dim3(NB, 3), 256, 0, stream>>>(cls0, cls1, cls2,
                                                reg0, reg1, reg2,
                                                cen0, cen1, cen2,
                                                boxes, labels, detws);
    final_kernel<<<1, 256, 0, stream>>>(segpart, detws, cls_pred, cls_target,
                                        (float*)d_out);
}

// Round 2
// 247.986 us; speedup vs baseline: 1.1622x; 1.1622x over previous
//
#include <hip/hip_runtime.h>
#include <math.h>

#define NB 32           // batch
#define SEG_BLOCKS 2048
#define DET_BLOCKS 96   // 3 scales * 32 images

// ---------- math helpers (match reference semantics) ----------

__device__ __forceinline__ float bce_logits(float x, float y) {
    // max(x,0) - x*y + log1p(exp(-|x|))
    float a = fabsf(x);
    return fmaxf(x, 0.f) - x * y + __logf(1.f + __expf(-a));
}

__device__ __forceinline__ float focal_elt(float x, float t) {
    // t is exactly 0.0 or 1.0 (one-hot)
    float p = 1.f / (1.f + __expf(-x));
    float ce = bce_logits(x, t);
    float p_t = (t > 0.5f) ? p : (1.f - p);
    float a_t = (t > 0.5f) ? 0.25f : 0.75f;
    float om = 1.f - p_t;
    return a_t * om * om * ce;
}

// Block reduction for N floats, blockDim.x == 256 (4 waves of 64).
template <int N>
__device__ void blk_reduce_arr(float* v) {
    __shared__ float sm[N][4];
    int lane = threadIdx.x & 63;
    int wid  = threadIdx.x >> 6;
#pragma unroll
    for (int j = 0; j < N; j++) {
        float x = v[j];
#pragma unroll
        for (int off = 32; off > 0; off >>= 1) x += __shfl_down(x, off, 64);
        if (lane == 0) sm[j][wid] = x;
    }
    __syncthreads();
    if (threadIdx.x == 0) {
#pragma unroll
        for (int j = 0; j < N; j++) {
            float s = 0.f;
#pragma unroll
            for (int w = 0; w < 4; w++) s += sm[j][w];
            v[j] = s;
        }
    }
}

// ---------- fused: det (blocks 0..95) + seg grid-stride (all blocks) ----------
// detc[s*NB+b] = (cls_l + reg_l + cen_l) / 96   (pre-scaled det contribution)
// segpart[blk] = raw BCE sum over this block's slice

__global__ __launch_bounds__(256) void fused_kernel(
        const float* __restrict__ seg_logits, const int* __restrict__ mask,
        const float* __restrict__ cls0, const float* __restrict__ cls1, const float* __restrict__ cls2,
        const float* __restrict__ reg0, const float* __restrict__ reg1, const float* __restrict__ reg2,
        const float* __restrict__ cen0, const float* __restrict__ cen1, const float* __restrict__ cen2,
        const float* __restrict__ boxes, const int* __restrict__ labels,
        float* __restrict__ segpart, float* __restrict__ detc) {

    // ===== det part: first 96 blocks, one (scale, image) each =====
    if (blockIdx.x < DET_BLOCKS) {
        const int s = blockIdx.x >> 5;   // 0..2
        const int b = blockIdx.x & 31;   // 0..31
        int Wd, shift, L; float stride;
        const float *cls, *reg, *cen;
        if (s == 0)      { Wd = 64; shift = 6; L = 4096; stride = 8.f;  cls = cls0; reg = reg0; cen = cen0; }
        else if (s == 1) { Wd = 32; shift = 5; L = 1024; stride = 16.f; cls = cls1; reg = reg1; cen = cen1; }
        else             { Wd = 16; shift = 4; L = 256;  stride = 32.f; cls = cls2; reg = reg2; cen = cen2; }

        __shared__ float sx0[20], sy0[20], sx1[20], sy1[20], sar[20];
        __shared__ int   slb[20];
        if (threadIdx.x < 20) {
            int k = threadIdx.x;
            const float* bb = boxes + (b * 20 + k) * 4;
            float cx = bb[0] * 512.f, cy = bb[1] * 512.f;
            float w  = bb[2] * 512.f, h  = bb[3] * 512.f;
            float x0 = cx - 0.5f * w, y0 = cy - 0.5f * h;
            float x1 = cx + 0.5f * w, y1 = cy + 0.5f * h;
            sx0[k] = x0; sy0[k] = y0; sx1[k] = x1; sy1[k] = y1;
            sar[k] = (x1 - x0) * (y1 - y0);
            slb[k] = labels[b * 20 + k];
        }
        __syncthreads();

        const float* clsb = cls + (size_t)b * 5 * L;
        const float* regb = reg + (size_t)b * 4 * L;
        const float* cenb = cen + (size_t)b * L;
        const float inv = 1.f / stride;

        float cls_s = 0.f, reg_s = 0.f, cen_s = 0.f, np = 0.f;
        for (int l = threadIdx.x; l < L; l += 256) {
            float lx = ((l & (Wd - 1)) + 0.5f) * stride;
            float ly = ((l >> shift)   + 0.5f) * stride;
            int bk = -1; float ba = INFINITY;
            float bl = 0.f, btp = 0.f, brr = 0.f, bbt = 0.f;
#pragma unroll
            for (int k = 0; k < 20; k++) {
                float li = lx - sx0[k], ti = ly - sy0[k];
                float ri = sx1[k] - lx, bi = sy1[k] - ly;
                float mn = fminf(fminf(li, ti), fminf(ri, bi));
                if (mn > 0.f && sar[k] < ba) {   // strict '<' == first-occurrence argmin
                    ba = sar[k]; bk = k;
                    bl = li; btp = ti; brr = ri; bbt = bi;
                }
            }
            int tl = (bk >= 0) ? slb[bk] : -1;
#pragma unroll
            for (int c = 0; c < 4; c++) {
                float x = clsb[(c + 1) * L + l];   // channel 0 dropped by reference
                cls_s += focal_elt(x, (c == tl) ? 1.f : 0.f);
            }
            if (bk >= 0) {
                float r0 = bl * inv, r1 = btp * inv, r2 = brr * inv, r3 = bbt * inv;
                float d0 = regb[0 * L + l] - r0;
                float d1 = regb[1 * L + l] - r1;
                float d2 = regb[2 * L + l] - r2;
                float d3 = regb[3 * L + l] - r3;
                float a0 = fabsf(d0), a1 = fabsf(d1), a2 = fabsf(d2), a3 = fabsf(d3);
                float sl = (a0 < 1.f ? 0.5f * d0 * d0 : a0 - 0.5f)
                         + (a1 < 1.f ? 0.5f * d1 * d1 : a1 - 0.5f)
                         + (a2 < 1.f ? 0.5f * d2 * d2 : a2 - 0.5f)
                         + (a3 < 1.f ? 0.5f * d3 * d3 : a3 - 0.5f);
                reg_s += 0.25f * sl;
                float mnlr = fminf(r0, r2), mxlr = fmaxf(r0, r2);
                float mntb = fminf(r1, r3), mxtb = fmaxf(r1, r3);
                float v = (mnlr / (mxlr + 1e-6f)) * (mntb / (mxtb + 1e-6f));
                v = fminf(fmaxf(v, 0.f), 1.f);
                float ct = sqrtf(v);
                cen_s += bce_logits(cenb[l], ct);
                np += 1.f;
            }
        }

        float v4[4] = {cls_s, reg_s, cen_s, np};
        blk_reduce_arr<4>(v4);
        if (threadIdx.x == 0) {
            float cls_l = v4[0] / (L * 4.f);
            float npos  = v4[3];
            float denom = fmaxf(npos, 1.f);
            float reg_l = (npos > 0.f) ? v4[1] / denom : 0.f;
            float cen_l = (npos > 0.f) ? v4[2] / denom : 0.f;
            detc[blockIdx.x] = (cls_l + reg_l + cen_l) * (1.f / (float)DET_BLOCKS);
        }
        __syncthreads();   // protect shared box arrays / reduce buffers before seg reduce
    }

    // ===== seg part: grid-stride over all (b, hw-quad) =====
    const int HW  = 512 * 512;   // 262144
    const int QPI = HW / 4;      // 65536 quads per image
    const int TOTQ = NB * QPI;   // 2,097,152
    int tid = blockIdx.x * 256 + threadIdx.x;
    float acc = 0.f;
    for (int q = tid; q < TOTQ; q += SEG_BLOCKS * 256) {
        int b   = q >> 16;       // q / 65536
        int hwq = q & 65535;
        const int4 m4 = ((const int4*)(mask + (size_t)b * HW))[hwq];
        float ty0 = (float)m4.x, ty1 = (float)m4.y, ty2 = (float)m4.z, ty3 = (float)m4.w;
        const float4* base = (const float4*)(seg_logits + (size_t)b * 4 * HW);
#pragma unroll
        for (int c = 0; c < 4; c++) {
            float4 x4 = base[c * QPI + hwq];
            acc += bce_logits(x4.x, ty0) + bce_logits(x4.y, ty1)
                 + bce_logits(x4.z, ty2) + bce_logits(x4.w, ty3);
        }
    }
    float v[1] = {acc};
    blk_reduce_arr<1>(v);
    if (threadIdx.x == 0) segpart[blockIdx.x] = v[0];
}

// ---------- final combine: all terms pre-scaled, one accumulator ----------

__global__ __launch_bounds__(256) void final_kernel(
        const float* __restrict__ segpart, const float* __restrict__ detc,
        const float* __restrict__ cls_pred, const int* __restrict__ cls_target,
        float* __restrict__ out) {
    const float seg_scale = 1.f / 33554432.f;   // B*4*512*512 (2^-25, exact)
    const float cls_scale = 0.5f / 320.f;       // W_CLS / (B*10)
    float acc = 0.f;
    for (int i = threadIdx.x; i < SEG_BLOCKS; i += 256) acc += segpart[i] * seg_scale;
    if (threadIdx.x < DET_BLOCKS) acc += detc[threadIdx.x];
    for (int e = threadIdx.x; e < NB * 10; e += 256) {
        int i = e / 10, c = e - i * 10;
        acc += cls_scale * focal_elt(cls_pred[e], (cls_target[i] == c) ? 1.f : 0.f);
    }
    float v[1] = {acc};
    blk_reduce_arr<1>(v);
    if (threadIdx.x == 0) out[0] = v[0];
}

// ---------- launch ----------

extern "C" void kernel_launch(void* const* d_in, const int* in_sizes, int n_in,
                              void* d_out, int out_size, void* d_ws, size_t ws_size,
                              hipStream_t stream) {
    const float* seg_logits = (const float*)d_in[0];
    const int*   seg_mask   = (const int*)d_in[1];
    const float* cls0 = (const float*)d_in[2];
    const float* cls1 = (const float*)d_in[3];
    const float* cls2 = (const float*)d_in[4];
    const float* reg0 = (const float*)d_in[5];
    const float* reg1 = (const float*)d_in[6];
    const float* reg2 = (const float*)d_in[7];
    const float* cen0 = (const float*)d_in[8];
    const float* cen1 = (const float*)d_in[9];
    const float* cen2 = (const float*)d_in[10];
    const float* boxes  = (const float*)d_in[11];
    const int*   labels = (const int*)d_in[12];
    const float* cls_pred   = (const float*)d_in[13];
    const int*   cls_target = (const int*)d_in[14];

    float* ws      = (float*)d_ws;
    float* segpart = ws;                 // SEG_BLOCKS floats
    float* detc    = ws + SEG_BLOCKS;    // DET_BLOCKS floats

    fused_kernel<<<SEG_BLOCKS, 256, 0, stream>>>(seg_logits, seg_mask,
                                                 cls0, cls1, cls2,
                                                 reg0, reg1, reg2,
                                                 cen0, cen1, cen2,
                                                 boxes, labels, segpart, detc);
    final_kernel<<<1, 256, 0, stream>>>(segpart, detc, cls_pred, cls_target,
                                        (float*)d_out);
}